// Round 9
// baseline (478.625 us; speedup 1.0000x reference)
//
#include <hip/hip_runtime.h>
#include <stdint.h>

#define D 128

typedef __attribute__((ext_vector_type(8))) short bf16x8;
typedef __attribute__((ext_vector_type(4))) float f32x4;
typedef __attribute__((ext_vector_type(2))) float f32x2;
typedef unsigned short u16;
typedef unsigned char u8;
typedef unsigned int u32;

// folded into Tk at projection time: 1/sqrt(128) * log2(e)  [validated R4-R8]
#define KSCALE (0.08838834764831845f * 1.4426950408889634f)

#if defined(__has_builtin)
#if __has_builtin(__builtin_amdgcn_cvt_pk_f32_fp8) && __has_builtin(__builtin_amdgcn_cvt_pk_fp8_f32)
#define HW_FP8 1
#endif
#if __has_builtin(__builtin_elementwise_fma)
#define VFMA(a, b, c) __builtin_elementwise_fma(a, b, c)
#else
#define VFMA(a, b, c) ((a) * (b) + (c))
#endif
#else
#define VFMA(a, b, c) ((a) * (b) + (c))
#endif

static __device__ __forceinline__ float b2f(u16 u) {
  return __uint_as_float(((unsigned)u) << 16);
}
static __device__ __forceinline__ u16 f2b(float f) {
  unsigned u = __float_as_uint(f);
  return (u16)((u + 0x7fffu + ((u >> 16) & 1u)) >> 16);
}

// ------------------------------ fp8 e4m3 -----------------------------------
static __device__ __forceinline__ u8 enc_fp8(float f) {
#ifdef HW_FP8
  int p = __builtin_amdgcn_cvt_pk_fp8_f32(f, 0.f, 0, false);
  return (u8)(p & 0xff);
#else
  float a = fabsf(f);
  unsigned s = (__float_as_uint(f) >> 31) << 7;
  if (a < 7.8125e-3f) {
    int m = (int)(a * 512.f + 0.5f);
    if (m > 7) m = 7;
    return (u8)(s | m);
  }
  int e; float mant = frexpf(a, &e);
  int E = e + 6;
  int m = (int)((2.f * mant - 1.f) * 8.f + 0.5f);
  if (m == 8) { m = 0; E++; }
  if (E > 15 || (E == 15 && m > 6)) { E = 15; m = 6; }
  if (E < 1) return (u8)s;
  return (u8)(s | (E << 3) | m);
#endif
}

static __device__ __forceinline__ float dec1_fp8(u8 b) {
  int e = (b >> 3) & 15, m = b & 7;
  float mag = e ? ldexpf((float)(8 + m), e - 10) : ldexpf((float)m, -9);
  return (b & 128) ? -mag : mag;
}

// decode 8 fp8 -> 4 x f32x2 (cvt_pk emits packed pairs natively)
static __device__ __forceinline__ void dec8_fp8_v(u32 lo, u32 hi, f32x2* o) {
#ifdef HW_FP8
  o[0] = __builtin_amdgcn_cvt_pk_f32_fp8((int)lo, false);
  o[1] = __builtin_amdgcn_cvt_pk_f32_fp8((int)lo, true);
  o[2] = __builtin_amdgcn_cvt_pk_f32_fp8((int)hi, false);
  o[3] = __builtin_amdgcn_cvt_pk_f32_fp8((int)hi, true);
#else
  u32 w[2] = {lo, hi};
  u8* p = (u8*)w;
#pragma unroll
  for (int i = 0; i < 4; ++i) o[i] = (f32x2){dec1_fp8(p[2 * i]), dec1_fp8(p[2 * i + 1])};
#endif
}

// DPP-based add from another lane (row of 16). CTRL must be an ICE.
// 0xB1 = quad_perm(1,0,3,2) -> lane^1 ; 0x4E = quad_perm(2,3,0,1) -> lane^2
// 0x128 = row_ror:8 ; 0x124 = row_ror:4
// (hardware-validated R1-R8)
template <int CTRL>
static __device__ __forceinline__ float dpp_add_f(float x) {
  int y = __builtin_amdgcn_update_dpp(0, __float_as_int(x), CTRL, 0xf, 0xf, true);
  return x + __int_as_float(y);
}

// ---------------------------------------------------------------------------
// Fused q-projection weight: M[d][j] = sum_c qw[c][d]*W[c][j] (qW = x@M).
// Stored transposed Mt[c][j][d]; fused bias bq[c][j] = qb @ W.
// ---------------------------------------------------------------------------
__global__ void prep_fused(const float* __restrict__ qwu, const float* __restrict__ qbu,
                           const float* __restrict__ qwi, const float* __restrict__ qbi,
                           const float* __restrict__ Wui, const float* __restrict__ Wiu,
                           u16* __restrict__ Mt, float* __restrict__ bq) {
  int c = blockIdx.y, d = blockIdx.x, j = threadIdx.x;
  int l = c & 1, type = c >> 1;
  const float* qw = (type ? qwi : qwu) + l * D * D;
  const float* qb = (type ? qbi : qbu) + l * D;
  const float* W  = (type ? Wiu : Wui) + l * D * D;
  float acc = 0.f;
  for (int cc = 0; cc < D; ++cc) acc += qw[cc * D + d] * W[cc * D + j];
  Mt[((size_t)c * D + j) * D + d] = f2b(acc);
  if (d == 0) {
    float ba = 0.f;
    for (int cc = 0; cc < D; ++cc) ba += qb[cc] * W[cc * D + j];
    bq[c * D + j] = ba;
  }
}

__global__ void cast_w(const float* __restrict__ kwu, const float* __restrict__ kwi,
                       const float* __restrict__ vwu, const float* __restrict__ vwi,
                       u16* __restrict__ Wb) {
  int y = blockIdx.y;
  const float* s = (y == 0) ? kwu : (y == 1) ? kwi : (y == 2) ? vwu : vwi;
  int i = blockIdx.x * 256 + threadIdx.x;
  Wb[(size_t)y * 2 * D * D + i] = f2b(s[i]);
}

__global__ void cast_x(const float* __restrict__ x, u16* __restrict__ xb, int n2) {
  int i = blockIdx.x * 256 + threadIdx.x;
  if (i < n2) {
    float2 v = ((const float2*)x)[i];
    ((unsigned*)xb)[i] = (unsigned)f2b(v.x) | ((unsigned)f2b(v.y) << 16);
  }
}

__global__ void zero_i(int* __restrict__ p, int n) {
  int i = blockIdx.x * 256 + threadIdx.x;
  if (i < n) p[i] = 0;
}

// --------------------- CSR build via 2-level bucket sort --------------------
__global__ __launch_bounds__(256) void bhist(const int* __restrict__ dui,
                                             const int* __restrict__ diu,
                                             int* __restrict__ cnt_ui,
                                             int* __restrict__ cnt_iu, int E) {
  __shared__ int h[256];
  int t = threadIdx.x;
  h[t] = 0;
  __syncthreads();
  const int* dp = blockIdx.y ? diu : dui;
  int e0 = blockIdx.x * 1024;
#pragma unroll
  for (int i = 0; i < 4; ++i) {
    int e = e0 + i * 256 + t;
    if (e < E) atomicAdd(&h[dp[e] >> 8], 1);
  }
  __syncthreads();
  int* out = blockIdx.y ? cnt_iu : cnt_ui;
  if (h[t]) atomicAdd(&out[t], h[t]);
}

__global__ __launch_bounds__(256) void bscan(const int* __restrict__ cnt_ui,
                                             const int* __restrict__ cnt_iu,
                                             int* __restrict__ base_ui, int* __restrict__ base_iu,
                                             int* __restrict__ cur_ui, int* __restrict__ cur_iu,
                                             int* __restrict__ rp_ui, int* __restrict__ rp_iu,
                                             int nb_ui, int nb_iu, int n_ui, int n_iu, int E) {
  __shared__ int sh[256];
  int t = threadIdx.x;
  int v = (t < nb_ui) ? cnt_ui[t] : 0;
  sh[t] = v;
  __syncthreads();
  for (int off = 1; off < 256; off <<= 1) {
    int u = (t >= off) ? sh[t - off] : 0;
    __syncthreads();
    sh[t] += u;
    __syncthreads();
  }
  int ex = sh[t] - v;
  if (t < nb_ui) { base_ui[t] = ex; cur_ui[t] = ex; }
  if (t == 0) { base_ui[nb_ui] = E; rp_ui[n_ui] = E; }
  __syncthreads();
  v = (t < nb_iu) ? cnt_iu[t] : 0;
  sh[t] = v;
  __syncthreads();
  for (int off = 1; off < 256; off <<= 1) {
    int u = (t >= off) ? sh[t - off] : 0;
    __syncthreads();
    sh[t] += u;
    __syncthreads();
  }
  ex = sh[t] - v;
  if (t < nb_iu) { base_iu[t] = ex; cur_iu[t] = ex; }
  if (t == 0) { base_iu[nb_iu] = E; rp_iu[n_iu] = E; }
}

__global__ __launch_bounds__(256) void bscatter(
    const int* __restrict__ sui, const int* __restrict__ dui,
    const int* __restrict__ siu, const int* __restrict__ diu,
    int* __restrict__ cur_ui, int* __restrict__ cur_iu,
    u32* __restrict__ bb_ui, u32* __restrict__ bb_iu, int E) {
  __shared__ int h[256], rbase[256], c2[256];
  int t = threadIdx.x;
  const int* sp = blockIdx.y ? siu : sui;
  const int* dp = blockIdx.y ? diu : dui;
  int* gc = blockIdx.y ? cur_iu : cur_ui;
  u32* bb = blockIdx.y ? bb_iu : bb_ui;
  h[t] = 0;
  c2[t] = 0;
  __syncthreads();
  int e0 = blockIdx.x * 1024;
  u32 pr[4];
  int bk[4];
  bool act[4];
#pragma unroll
  for (int i = 0; i < 4; ++i) {
    int e = e0 + i * 256 + t;
    act[i] = e < E;
    if (act[i]) {
      int s = sp[e], d2 = dp[e];
      pr[i] = ((u32)d2 << 16) | (u32)s;
      bk[i] = d2 >> 8;
      atomicAdd(&h[bk[i]], 1);
    }
  }
  __syncthreads();
  if (h[t]) rbase[t] = atomicAdd(&gc[t], h[t]);
  __syncthreads();
#pragma unroll
  for (int i = 0; i < 4; ++i) {
    if (act[i]) {
      int r = atomicAdd(&c2[bk[i]], 1);
      bb[rbase[bk[i]] + r] = pr[i];
    }
  }
}

__global__ __launch_bounds__(256) void bsort(
    const u32* __restrict__ bb_ui, const u32* __restrict__ bb_iu,
    const int* __restrict__ base_ui, const int* __restrict__ base_iu,
    int* __restrict__ rp_ui, int* __restrict__ rp_iu,
    int* __restrict__ cs_ui, int* __restrict__ cs_iu,
    int nb_ui, int n_ui, int n_iu) {
  int b = blockIdx.x;
  const u32* bb; const int* base; int* rp; int* cs; int n;
  if (b < nb_ui) { bb = bb_ui; base = base_ui; rp = rp_ui; cs = cs_ui; n = n_ui; }
  else { b -= nb_ui; bb = bb_iu; base = base_iu; rp = rp_iu; cs = cs_iu; n = n_iu; }
  int lo = base[b], hi = base[b + 1];
  __shared__ int h[256], sh[256], cur[256];
  int t = threadIdx.x;
  h[t] = 0;
  __syncthreads();
  for (int j = lo + t; j < hi; j += 256) atomicAdd(&h[(bb[j] >> 16) & 255], 1);
  __syncthreads();
  int v = h[t];
  sh[t] = v;
  __syncthreads();
  for (int off = 1; off < 256; off <<= 1) {
    int u = (t >= off) ? sh[t - off] : 0;
    __syncthreads();
    sh[t] += u;
    __syncthreads();
  }
  int ex = lo + sh[t] - v;
  int gd = (b << 8) + t;
  if (gd < n) rp[gd] = ex;
  cur[t] = ex;
  __syncthreads();
  for (int j = lo + t; j < hi; j += 256) {
    u32 pr = bb[j];
    int p = atomicAdd(&cur[(pr >> 16) & 255], 1);
    cs[p] = (int)(pr & 0xffffu);
  }
}

// ---------------------------------------------------------------------------
// Merged 3-way projection for BOTH node sets. blockIdx.x < gu -> users,
// else items. blockIdx.y: 0 -> q (fp8 into Tqv lo 8B-chunks), 1 -> k (bf16
// into Tk, PRE-SCALED by KSCALE = 1/sqrt(D)*log2(e)), 2 -> v (fp8 into Tqv
// hi 8B-chunks). Tqv row (256 B) INTERLEAVED (R7 layout, best measured for
// agg: single 16B gather/lane): [q0..7 | v0..7 | q8..15 | v8..15 | ...],
// dim group g (dims 8g..8g+7) -> bytes 16g+vo..16g+vo+7 (vo=0 q, 8 v).
// Epilogue: stage encoded bytes in reused wlds, then each thread emits
// 4 x 8B stores at stride 16 (vs pre-R8's 32 scattered 1-2B stores).
// MFMA layouts (m89/m91-verified): A[m=lane&15][k=quad*8+j];
// B[k=quad*8+j][n=lane&15]; C/D: col=lane&15, row=quad*4+reg.
// ---------------------------------------------------------------------------
__global__ __launch_bounds__(256) void gemm3(
    const u16* __restrict__ xu, const u16* __restrict__ xi,
    const u16* __restrict__ wqu, const u16* __restrict__ wku, const u16* __restrict__ wvu,
    const float* __restrict__ bqu, const float* __restrict__ bku, const float* __restrict__ bvu,
    const u16* __restrict__ wqi, const u16* __restrict__ wki, const u16* __restrict__ wvi,
    const float* __restrict__ bqi, const float* __restrict__ bki, const float* __restrict__ bvi,
    u8* __restrict__ Tqv_u, u16* __restrict__ Tk_u,
    u8* __restrict__ Tqv_i, u16* __restrict__ Tk_i,
    int gu, int nu, int ni) {
  __shared__ __align__(16) u16 wlds[128 * 136];
  int bx = blockIdx.x, y = blockIdx.y;
  bool item = bx >= gu;
  if (item) bx -= gu;
  const u16* x = item ? xi : xu;
  int nrows = item ? ni : nu;
  const u16* wt; const float* bias;
  if (y == 0)      { wt = item ? wqi : wqu; bias = item ? bqi : bqu; }
  else if (y == 1) { wt = item ? wki : wku; bias = item ? bki : bku; }
  else             { wt = item ? wvi : wvu; bias = item ? bvi : bvu; }
  u8* Tqv = item ? Tqv_i : Tqv_u;
  u16* Tk = item ? Tk_i : Tk_u;

  int t = threadIdx.x;
#pragma unroll
  for (int i = 0; i < 8; ++i) {
    int idx = t + 256 * i;
    int n = idx >> 4, kc = idx & 15;
    ((bf16x8*)wlds)[n * 17 + kc] = ((const bf16x8*)wt)[idx];
  }
  __syncthreads();
  int wave = t >> 6, lane = t & 63;
  int m = lane & 15, quad = lane >> 4;
  int row0 = bx * 64 + wave * 16;
  int arow = row0 + m;
  const bf16x8* xv = (const bf16x8*)(x + (size_t)(arow < nrows ? arow : 0) * D);
  f32x4 acc[8];
#pragma unroll
  for (int n = 0; n < 8; ++n) acc[n] = (f32x4){0.f, 0.f, 0.f, 0.f};
#pragma unroll
  for (int kk = 0; kk < 4; ++kk) {
    bf16x8 a = xv[kk * 4 + quad];
#pragma unroll
    for (int n = 0; n < 8; ++n) {
      bf16x8 b = ((const bf16x8*)wlds)[(n * 16 + m) * 17 + kk * 4 + quad];
      acc[n] = __builtin_amdgcn_mfma_f32_16x16x32_bf16(a, b, acc[n], 0, 0, 0);
    }
  }
  __syncthreads();  // all waves done reading weights; wlds is reused below
  if (y == 1) {
    u16* ob = (u16*)wlds;  // [64][136] u16 (stride 136: 16B-aligned rows)
#pragma unroll
    for (int n = 0; n < 8; ++n) {
      float bb = bias[n * 16 + m];
#pragma unroll
      for (int r = 0; r < 4; ++r) {
        int rl = wave * 16 + quad * 4 + r;
        ob[rl * 136 + n * 16 + m] = f2b((acc[n][r] + bb) * KSCALE);
      }
    }
    __syncthreads();
    int rl = t >> 2, c0 = (t & 3) * 32;
    int orow = bx * 64 + rl;
    if (orow < nrows) {
      const uint4* src = (const uint4*)(ob + rl * 136 + c0);
      uint4* dst = (uint4*)(Tk + (size_t)orow * 128 + c0);
      dst[0] = src[0]; dst[1] = src[1]; dst[2] = src[2]; dst[3] = src[3];
    }
  } else {
    int vo = (y == 0) ? 0 : 8;
    u8* ob = (u8*)wlds;  // [64][144] u8 (stride 144: 16B-aligned rows)
#pragma unroll
    for (int n = 0; n < 8; ++n) {
      float bb = bias[n * 16 + m];
#pragma unroll
      for (int r = 0; r < 4; ++r) {
        int rl = wave * 16 + quad * 4 + r;
        ob[rl * 144 + n * 16 + m] = enc_fp8(acc[n][r] + bb);
      }
    }
    __syncthreads();
    // thread covers dims [c0, c0+32) of row rl = 4 groups of 8 dims;
    // group g -> 8B at byte offset (c0/8+g)*16 + vo in the interleaved row
    int rl = t >> 2, c0 = (t & 3) * 32;
    int orow = bx * 64 + rl;
    if (orow < nrows) {
      const u8* src = ob + rl * 144 + c0;
      u8* dst = Tqv + (size_t)orow * 256 + (c0 >> 3) * 16 + vo;
#pragma unroll
      for (int g = 0; g < 4; ++g)
        *(uint2*)(dst + g * 16) = *(const uint2*)(src + g * 8);
    }
  }
}

// ---------------------------------------------------------------------------
// Per-edge-slot work (R7-exact): decode q|v fp8 from one uint4 to f32x2
// pairs, packed dot + horizontal add, DPP 16-lane reduce (broadcast),
// leaky_relu + exp2 (k pre-scaled by 1/sqrt(D)*log2e), packed acc.
// ---------------------------------------------------------------------------
static __device__ __forceinline__ void do_edge(uint4 w, bool act, const f32x2* kx,
                                               f32x2* acc, float& z) {
  f32x2 qx[4], vx[4];
  dec8_fp8_v(w.x, w.y, qx);
  dec8_fp8_v(w.z, w.w, vx);
  f32x2 d2 = qx[0] * kx[0];
  d2 = VFMA(qx[1], kx[1], d2);
  d2 = VFMA(qx[2], kx[2], d2);
  d2 = VFMA(qx[3], kx[3], d2);
  float dot = d2.x + d2.y;
  dot = dpp_add_f<0xB1>(dot);   // + lane^1
  dot = dpp_add_f<0x4E>(dot);   // + lane^2  -> quad-of-4 uniform
  dot = dpp_add_f<0x128>(dot);  // + row_ror:8
  dot = dpp_add_f<0x124>(dot);  // + row_ror:4 -> full 16-lane sum, broadcast
  float sc = (dot > 0.f) ? dot : 0.01f * dot;  // leaky_relu (scale pre-folded)
  float p = act ? exp2f(sc) : 0.f;             // exp(leaky(score)) == exp2(sc)
  z += p;
  f32x2 p2 = {p, p};
  acc[0] = VFMA(p2, vx[0], acc[0]);
  acc[1] = VFMA(p2, vx[1], acc[1]);
  acc[2] = VFMA(p2, vx[2], acc[2]);
  acc[3] = VFMA(p2, vx[3], acc[3]);
}

// ---------------------------------------------------------------------------
// Merged CSR aggregation: R7-exact (best measured: 59.7us, FETCH 130MB).
// ONE WAVE PER DST, 16 edge slots/iter, wave-uniform rem guards, single
// 16B gather per lane per slot from the interleaved q|v row, nontemporal
// agg stores.
// ---------------------------------------------------------------------------
__global__ __launch_bounds__(256, 8) void agg_pass(
    const u8* __restrict__ Tqv_u, const u16* __restrict__ Tk_u,
    const u8* __restrict__ Tqv_i, const u16* __restrict__ Tk_i,
    const int* __restrict__ rp_ui, const int* __restrict__ cs_ui,
    const int* __restrict__ rp_iu, const int* __restrict__ cs_iu,
    float* __restrict__ agg_u, float* __restrict__ agg_i,
    float* __restrict__ zpart, int gai, int ni, int nu) {
  int bx = blockIdx.x;
  const u8* Pqv; const u16* Pk; const int* rp; const int* cs;
  float* agg; float* zp; int ndst;
  if (bx < gai) { Pqv = Tqv_u; Pk = Tk_i; rp = rp_ui; cs = cs_ui; agg = agg_i; zp = zpart; ndst = ni; }
  else { bx -= gai; Pqv = Tqv_i; Pk = Tk_u; rp = rp_iu; cs = cs_iu; agg = agg_u; zp = zpart + 1024; ndst = nu; }
  int wave = threadIdx.x >> 6, lane = threadIdx.x & 63;
  int d = bx * 4 + wave;
  int sub = lane & 15;
  int quad = lane >> 4;
  float z = 0.f;
  f32x2 acc[4] = {{0.f, 0.f}, {0.f, 0.f}, {0.f, 0.f}, {0.f, 0.f}};
  if (d < ndst) {
    bf16x8 kf = *(const bf16x8*)(Pk + (size_t)d * D + sub * 8);
    int beg = rp[d], end = rp[d + 1];
    f32x2 kx[4];
#pragma unroll
    for (int i = 0; i < 4; ++i)
      kx[i] = (f32x2){b2f((u16)((short*)&kf)[2 * i]), b2f((u16)((short*)&kf)[2 * i + 1])};
    const u8* Pq = Pqv + sub * 16;
    for (int j = beg; j < end; j += 16) {
      int rem = end - j;  // wave-uniform (>0)
      int e1 = end - 1;
      int i0 = j + quad, i1 = i0 + 4, i2 = i0 + 8, i3 = i0 + 12;
      int s0 = cs[i0 < end ? i0 : e1];
      int s1 = cs[i1 < end ? i1 : e1];
      int s2 = cs[i2 < end ? i2 : e1];
      int s3 = cs[i3 < end ? i3 : e1];
      // four independent 16B gathers in flight before first use
      uint4 w0 = *(const uint4*)(Pq + (size_t)s0 * 256);
      uint4 w1 = *(const uint4*)(Pq + (size_t)s1 * 256);
      uint4 w2 = *(const uint4*)(Pq + (size_t)s2 * 256);
      uint4 w3 = *(const uint4*)(Pq + (size_t)s3 * 256);
      do_edge(w0, i0 < end, kx, acc, z);
      if (rem > 4)  do_edge(w1, i1 < end, kx, acc, z);
      if (rem > 8)  do_edge(w2, i2 < end, kx, acc, z);
      if (rem > 12) do_edge(w3, i3 < end, kx, acc, z);
    }
    float* af = (float*)acc;
#pragma unroll
    for (int i = 0; i < 8; ++i) {
      af[i] += __shfl_xor(af[i], 16, 64);
      af[i] += __shfl_xor(af[i], 32, 64);
    }
    if (quad == 0) {
      float* ap = agg + (size_t)d * D + sub * 8;
      __builtin_nontemporal_store((f32x4){af[0], af[1], af[2], af[3]}, (f32x4*)ap);
      __builtin_nontemporal_store((f32x4){af[4], af[5], af[6], af[7]}, (f32x4*)ap + 1);
    }
    z += __shfl_xor(z, 16, 64);
    z += __shfl_xor(z, 32, 64);
  }
  __shared__ float ps[4];
  if (lane == 0) ps[wave] = z;
  __syncthreads();
  if (threadIdx.x == 0)
    unsafeAtomicAdd(&zp[blockIdx.x & 1023], ps[0] + ps[1] + ps[2] + ps[3]);
}

// float4-vectorized, with the z reduction folded in (validated R8): each
// block redundantly reduces zpart[0..2047] (8KB, L2-resident) — removes the
// zreduce launch + serialization hop.
__global__ void update_x(const float* __restrict__ xu, const float* __restrict__ xi,
                         const float* __restrict__ aggu, const float* __restrict__ aggi,
                         const float* __restrict__ zpart,
                         float* __restrict__ ou, float* __restrict__ oi,
                         u16* __restrict__ bu, u16* __restrict__ bi,
                         int nu4, int ni4, int wb) {
  __shared__ float red0[256], red1[256];
  int t = threadIdx.x;
  float s0 = zpart[t] + zpart[t + 256] + zpart[t + 512] + zpart[t + 768];
  float s1 = zpart[1024 + t] + zpart[1280 + t] + zpart[1536 + t] + zpart[1792 + t];
  red0[t] = s0;
  red1[t] = s1;
  __syncthreads();
  for (int k = 128; k > 0; k >>= 1) {
    if (t < k) { red0[t] += red0[t + k]; red1[t] += red1[t + k]; }
    __syncthreads();
  }
  float zi = 1.0f / red0[0];  // ui edges -> item aggregation normalizer
  float zu = 1.0f / red1[0];  // iu edges -> user aggregation normalizer
  int i = blockIdx.x * 256 + t;
  const float4* xs; const float4* as; float4* os; u16* bs; float zz; int jj;
  if (i < nu4) {
    xs = (const float4*)xu; as = (const float4*)aggu; os = (float4*)ou; bs = bu;
    zz = zu; jj = i;
  } else if (i < nu4 + ni4) {
    jj = i - nu4;
    xs = (const float4*)xi; as = (const float4*)aggi; os = (float4*)oi; bs = bi;
    zz = zi;
  } else {
    return;
  }
  float4 xv = xs[jj];
  float4 av = as[jj];
  float4 v;
  v.x = xv.x + av.x * zz;
  v.y = xv.y + av.y * zz;
  v.z = xv.z + av.z * zz;
  v.w = xv.w + av.w * zz;
  os[jj] = v;
  if (wb) {
    ushort4 b;
    b.x = f2b(v.x); b.y = f2b(v.y); b.z = f2b(v.z); b.w = f2b(v.w);
    ((ushort4*)bs)[jj] = b;
  }
}

extern "C" void kernel_launch(void* const* d_in, const int* in_sizes, int n_in,
                              void* d_out, int out_size, void* d_ws, size_t ws_size,
                              hipStream_t stream) {
  const float* xu_in = (const float*)d_in[0];
  const float* xi_in = (const float*)d_in[1];
  const int* ei_ui = (const int*)d_in[2];
  const int* ei_iu = (const int*)d_in[3];
  const float* qwu = (const float*)d_in[4];
  const float* qbu = (const float*)d_in[5];
  const float* kwu = (const float*)d_in[6];
  const float* kbu = (const float*)d_in[7];
  const float* vwu = (const float*)d_in[8];
  const float* vbu = (const float*)d_in[9];
  const float* qwi = (const float*)d_in[10];
  const float* qbi = (const float*)d_in[11];
  const float* kwi = (const float*)d_in[12];
  const float* kbi = (const float*)d_in[13];
  const float* vwi = (const float*)d_in[14];
  const float* vbi = (const float*)d_in[15];
  const float* Wui = (const float*)d_in[16];
  const float* Wiu = (const float*)d_in[17];

  int NU = in_sizes[0] / D;
  int NI = in_sizes[1] / D;
  int E  = in_sizes[2] / 2;

  // workspace layout (16B-aligned chunks)
  char* w = (char*)d_ws;
  float* agg_u = (float*)w;  w += (size_t)NU * D * 4;
  float* agg_i = (float*)w;  w += (size_t)NI * D * 4;
  // zero region: bcnt_ui[256], bcnt_iu[256], zpart[4096] contiguous
  int* bcnt_ui = (int*)w;    w += 256 * 4;
  int* bcnt_iu = (int*)w;    w += 256 * 4;
  float* zpart = (float*)w;  w += 4096 * 4;
  float* bq    = (float*)w;  w += 4 * D * 4;
  int* base_ui = (int*)w;    w += 260 * 4;
  int* base_iu = (int*)w;    w += 260 * 4;
  int* cur_ui  = (int*)w;    w += 256 * 4;
  int* cur_iu  = (int*)w;    w += 256 * 4;
  int* rp_ui = (int*)w;      w += (size_t)(NI + 4) * 4;
  int* rp_iu = (int*)w;      w += (size_t)(NU + 4) * 4;
  int* cs_ui = (int*)w;      w += (size_t)E * 4;
  int* cs_iu = (int*)w;      w += (size_t)E * 4;
  u32* bb_ui = (u32*)w;      w += (size_t)E * 4;
  u32* bb_iu = (u32*)w;      w += (size_t)E * 4;
  u16* Mt  = (u16*)w;        w += (size_t)4 * D * D * 2;
  u16* Wb  = (u16*)w;        w += (size_t)8 * D * D * 2;
  u16* xub = (u16*)w;        w += (size_t)NU * D * 2;
  u16* xib = (u16*)w;        w += (size_t)NI * D * 2;
  u16* Tk_u = (u16*)w;       w += (size_t)NU * D * 2;
  u16* Tk_i = (u16*)w;       w += (size_t)NI * D * 2;
  u8* Tqv_u = (u8*)w;        w += (size_t)NU * 256;
  u8* Tqv_i = (u8*)w;

  float* out_u = (float*)d_out;
  float* out_i = out_u + (size_t)NU * D;

  prep_fused<<<dim3(128, 4), 128, 0, stream>>>(qwu, qbu, qwi, qbi, Wui, Wiu, Mt, bq);
  cast_w<<<dim3(128, 4), 256, 0, stream>>>(kwu, kwi, vwu, vwi, Wb);
  cast_x<<<(NU * D / 2 + 255) / 256, 256, 0, stream>>>(xu_in, xub, NU * D / 2);
  cast_x<<<(NI * D / 2 + 255) / 256, 256, 0, stream>>>(xi_in, xib, NI * D / 2);

  // ---- CSR build via 2-level bucket sort (edges constant across layers) ----
  int nb_ui = (NI + 255) >> 8;
  int nb_iu = (NU + 255) >> 8;
  zero_i<<<18, 256, 0, stream>>>(bcnt_ui, 512 + 4096);
  int geb = (E + 1023) / 1024;
  bhist<<<dim3(geb, 2), 256, 0, stream>>>(ei_ui + E, ei_iu + E, bcnt_ui, bcnt_iu, E);
  bscan<<<1, 256, 0, stream>>>(bcnt_ui, bcnt_iu, base_ui, base_iu, cur_ui, cur_iu,
                               rp_ui, rp_iu, nb_ui, nb_iu, NI, NU, E);
  bscatter<<<dim3(geb, 2), 256, 0, stream>>>(ei_ui, ei_ui + E, ei_iu, ei_iu + E,
                                             cur_ui, cur_iu, bb_ui, bb_iu, E);
  bsort<<<nb_ui + nb_iu, 256, 0, stream>>>(bb_ui, bb_iu, base_ui, base_iu,
                                           rp_ui, rp_iu, cs_ui, cs_iu, nb_ui, NI, NU);

  int gu = (NU + 63) / 64, gi = (NI + 63) / 64;
  int gau = (NU + 3) / 4, gai = (NI + 3) / 4;
  int nu4 = NU * D / 4, ni4 = NI * D / 4;
  int gup = (nu4 + ni4 + 255) / 256;

  for (int l = 0; l < 2; ++l) {
    gemm3<<<dim3(gu + gi, 3), 256, 0, stream>>>(
        xub, xib,
        Mt + (size_t)l * D * D, Wb + (size_t)(0 + l) * D * D, Wb + (size_t)(4 + l) * D * D,
        bq + l * D, kbu + l * D, vbu + l * D,
        Mt + (size_t)(2 + l) * D * D, Wb + (size_t)(2 + l) * D * D, Wb + (size_t)(6 + l) * D * D,
        bq + (2 + l) * D, kbi + l * D, vbi + l * D,
        Tqv_u, Tk_u, Tqv_i, Tk_i, gu, NU, NI);
    agg_pass<<<gai + gau, 256, 0, stream>>>(
        Tqv_u, Tk_u, Tqv_i, Tk_i, rp_ui, cs_ui, rp_iu, cs_iu,
        agg_u, agg_i, zpart + (size_t)l * 2 * 1024, gai, NI, NU);
    if (l == 0)
      update_x<<<gup, 256, 0, stream>>>(xu_in, xi_in, agg_u, agg_i,
                                        zpart + (size_t)l * 2 * 1024,
                                        out_u, out_i, xub, xib, nu4, ni4, 1);
    else
      update_x<<<gup, 256, 0, stream>>>(out_u, out_i, agg_u, agg_i,
                                        zpart + (size_t)l * 2 * 1024,
                                        out_u, out_i, nullptr, nullptr, nu4, ni4, 0);
  }
}

// Round 10
// 450.878 us; speedup vs baseline: 1.0615x; 1.0615x over previous
//
#include <hip/hip_runtime.h>
#include <stdint.h>

#define D 128

typedef __attribute__((ext_vector_type(8))) short bf16x8;
typedef __attribute__((ext_vector_type(4))) float f32x4;
typedef __attribute__((ext_vector_type(2))) float f32x2;
typedef unsigned short u16;
typedef unsigned char u8;
typedef unsigned int u32;

// folded into Tk at projection time: 1/sqrt(128) * log2(e)  [validated R4-R9]
#define KSCALE (0.08838834764831845f * 1.4426950408889634f)

#if defined(__has_builtin)
#if __has_builtin(__builtin_amdgcn_cvt_pk_f32_fp8) && __has_builtin(__builtin_amdgcn_cvt_pk_fp8_f32)
#define HW_FP8 1
#endif
#if __has_builtin(__builtin_elementwise_fma)
#define VFMA(a, b, c) __builtin_elementwise_fma(a, b, c)
#else
#define VFMA(a, b, c) ((a) * (b) + (c))
#endif
#else
#define VFMA(a, b, c) ((a) * (b) + (c))
#endif

static __device__ __forceinline__ float b2f(u16 u) {
  return __uint_as_float(((unsigned)u) << 16);
}
static __device__ __forceinline__ u16 f2b(float f) {
  unsigned u = __float_as_uint(f);
  return (u16)((u + 0x7fffu + ((u >> 16) & 1u)) >> 16);
}

// ------------------------------ fp8 e4m3 -----------------------------------
static __device__ __forceinline__ u8 enc_fp8(float f) {
#ifdef HW_FP8
  int p = __builtin_amdgcn_cvt_pk_fp8_f32(f, 0.f, 0, false);
  return (u8)(p & 0xff);
#else
  float a = fabsf(f);
  unsigned s = (__float_as_uint(f) >> 31) << 7;
  if (a < 7.8125e-3f) {
    int m = (int)(a * 512.f + 0.5f);
    if (m > 7) m = 7;
    return (u8)(s | m);
  }
  int e; float mant = frexpf(a, &e);
  int E = e + 6;
  int m = (int)((2.f * mant - 1.f) * 8.f + 0.5f);
  if (m == 8) { m = 0; E++; }
  if (E > 15 || (E == 15 && m > 6)) { E = 15; m = 6; }
  if (E < 1) return (u8)s;
  return (u8)(s | (E << 3) | m);
#endif
}

static __device__ __forceinline__ float dec1_fp8(u8 b) {
  int e = (b >> 3) & 15, m = b & 7;
  float mag = e ? ldexpf((float)(8 + m), e - 10) : ldexpf((float)m, -9);
  return (b & 128) ? -mag : mag;
}

// decode 8 fp8 -> 4 x f32x2 (cvt_pk emits packed pairs natively)
static __device__ __forceinline__ void dec8_fp8_v(u32 lo, u32 hi, f32x2* o) {
#ifdef HW_FP8
  o[0] = __builtin_amdgcn_cvt_pk_f32_fp8((int)lo, false);
  o[1] = __builtin_amdgcn_cvt_pk_f32_fp8((int)lo, true);
  o[2] = __builtin_amdgcn_cvt_pk_f32_fp8((int)hi, false);
  o[3] = __builtin_amdgcn_cvt_pk_f32_fp8((int)hi, true);
#else
  u32 w[2] = {lo, hi};
  u8* p = (u8*)w;
#pragma unroll
  for (int i = 0; i < 4; ++i) o[i] = (f32x2){dec1_fp8(p[2 * i]), dec1_fp8(p[2 * i + 1])};
#endif
}

// DPP-based add from another lane (row of 16). CTRL must be an ICE.
// 0xB1 = quad_perm(1,0,3,2) -> lane^1 ; 0x4E = quad_perm(2,3,0,1) -> lane^2
// 0x128 = row_ror:8 ; 0x124 = row_ror:4
// (hardware-validated R1-R9)
template <int CTRL>
static __device__ __forceinline__ float dpp_add_f(float x) {
  int y = __builtin_amdgcn_update_dpp(0, __float_as_int(x), CTRL, 0xf, 0xf, true);
  return x + __int_as_float(y);
}

// ---------------------------------------------------------------------------
// Fused q-projection weight: M[d][j] = sum_c qw[c][d]*W[c][j] (qW = x@M).
// Stored transposed Mt[c][j][d]; fused bias bq[c][j] = qb @ W.
// ---------------------------------------------------------------------------
__global__ void prep_fused(const float* __restrict__ qwu, const float* __restrict__ qbu,
                           const float* __restrict__ qwi, const float* __restrict__ qbi,
                           const float* __restrict__ Wui, const float* __restrict__ Wiu,
                           u16* __restrict__ Mt, float* __restrict__ bq) {
  int c = blockIdx.y, d = blockIdx.x, j = threadIdx.x;
  int l = c & 1, type = c >> 1;
  const float* qw = (type ? qwi : qwu) + l * D * D;
  const float* qb = (type ? qbi : qbu) + l * D;
  const float* W  = (type ? Wiu : Wui) + l * D * D;
  float acc = 0.f;
  for (int cc = 0; cc < D; ++cc) acc += qw[cc * D + d] * W[cc * D + j];
  Mt[((size_t)c * D + j) * D + d] = f2b(acc);
  if (d == 0) {
    float ba = 0.f;
    for (int cc = 0; cc < D; ++cc) ba += qb[cc] * W[cc * D + j];
    bq[c * D + j] = ba;
  }
}

__global__ void cast_w(const float* __restrict__ kwu, const float* __restrict__ kwi,
                       const float* __restrict__ vwu, const float* __restrict__ vwi,
                       u16* __restrict__ Wb) {
  int y = blockIdx.y;
  const float* s = (y == 0) ? kwu : (y == 1) ? kwi : (y == 2) ? vwu : vwi;
  int i = blockIdx.x * 256 + threadIdx.x;
  Wb[(size_t)y * 2 * D * D + i] = f2b(s[i]);
}

__global__ void cast_x(const float* __restrict__ x, u16* __restrict__ xb, int n2) {
  int i = blockIdx.x * 256 + threadIdx.x;
  if (i < n2) {
    float2 v = ((const float2*)x)[i];
    ((unsigned*)xb)[i] = (unsigned)f2b(v.x) | ((unsigned)f2b(v.y) << 16);
  }
}

__global__ void zero_i(int* __restrict__ p, int n) {
  int i = blockIdx.x * 256 + threadIdx.x;
  if (i < n) p[i] = 0;
}

// --------------------- CSR build via 2-level bucket sort --------------------
__global__ __launch_bounds__(256) void bhist(const int* __restrict__ dui,
                                             const int* __restrict__ diu,
                                             int* __restrict__ cnt_ui,
                                             int* __restrict__ cnt_iu, int E) {
  __shared__ int h[256];
  int t = threadIdx.x;
  h[t] = 0;
  __syncthreads();
  const int* dp = blockIdx.y ? diu : dui;
  int e0 = blockIdx.x * 1024;
#pragma unroll
  for (int i = 0; i < 4; ++i) {
    int e = e0 + i * 256 + t;
    if (e < E) atomicAdd(&h[dp[e] >> 8], 1);
  }
  __syncthreads();
  int* out = blockIdx.y ? cnt_iu : cnt_ui;
  if (h[t]) atomicAdd(&out[t], h[t]);
}

__global__ __launch_bounds__(256) void bscan(const int* __restrict__ cnt_ui,
                                             const int* __restrict__ cnt_iu,
                                             int* __restrict__ base_ui, int* __restrict__ base_iu,
                                             int* __restrict__ cur_ui, int* __restrict__ cur_iu,
                                             int* __restrict__ rp_ui, int* __restrict__ rp_iu,
                                             int nb_ui, int nb_iu, int n_ui, int n_iu, int E) {
  __shared__ int sh[256];
  int t = threadIdx.x;
  int v = (t < nb_ui) ? cnt_ui[t] : 0;
  sh[t] = v;
  __syncthreads();
  for (int off = 1; off < 256; off <<= 1) {
    int u = (t >= off) ? sh[t - off] : 0;
    __syncthreads();
    sh[t] += u;
    __syncthreads();
  }
  int ex = sh[t] - v;
  if (t < nb_ui) { base_ui[t] = ex; cur_ui[t] = ex; }
  if (t == 0) { base_ui[nb_ui] = E; rp_ui[n_ui] = E; }
  __syncthreads();
  v = (t < nb_iu) ? cnt_iu[t] : 0;
  sh[t] = v;
  __syncthreads();
  for (int off = 1; off < 256; off <<= 1) {
    int u = (t >= off) ? sh[t - off] : 0;
    __syncthreads();
    sh[t] += u;
    __syncthreads();
  }
  ex = sh[t] - v;
  if (t < nb_iu) { base_iu[t] = ex; cur_iu[t] = ex; }
  if (t == 0) { base_iu[nb_iu] = E; rp_iu[n_iu] = E; }
}

__global__ __launch_bounds__(256) void bscatter(
    const int* __restrict__ sui, const int* __restrict__ dui,
    const int* __restrict__ siu, const int* __restrict__ diu,
    int* __restrict__ cur_ui, int* __restrict__ cur_iu,
    u32* __restrict__ bb_ui, u32* __restrict__ bb_iu, int E) {
  __shared__ int h[256], rbase[256], c2[256];
  int t = threadIdx.x;
  const int* sp = blockIdx.y ? siu : sui;
  const int* dp = blockIdx.y ? diu : dui;
  int* gc = blockIdx.y ? cur_iu : cur_ui;
  u32* bb = blockIdx.y ? bb_iu : bb_ui;
  h[t] = 0;
  c2[t] = 0;
  __syncthreads();
  int e0 = blockIdx.x * 1024;
  u32 pr[4];
  int bk[4];
  bool act[4];
#pragma unroll
  for (int i = 0; i < 4; ++i) {
    int e = e0 + i * 256 + t;
    act[i] = e < E;
    if (act[i]) {
      int s = sp[e], d2 = dp[e];
      pr[i] = ((u32)d2 << 16) | (u32)s;
      bk[i] = d2 >> 8;
      atomicAdd(&h[bk[i]], 1);
    }
  }
  __syncthreads();
  if (h[t]) rbase[t] = atomicAdd(&gc[t], h[t]);
  __syncthreads();
#pragma unroll
  for (int i = 0; i < 4; ++i) {
    if (act[i]) {
      int r = atomicAdd(&c2[bk[i]], 1);
      bb[rbase[bk[i]] + r] = pr[i];
    }
  }
}

__global__ __launch_bounds__(256) void bsort(
    const u32* __restrict__ bb_ui, const u32* __restrict__ bb_iu,
    const int* __restrict__ base_ui, const int* __restrict__ base_iu,
    int* __restrict__ rp_ui, int* __restrict__ rp_iu,
    int* __restrict__ cs_ui, int* __restrict__ cs_iu,
    int nb_ui, int n_ui, int n_iu) {
  int b = blockIdx.x;
  const u32* bb; const int* base; int* rp; int* cs; int n;
  if (b < nb_ui) { bb = bb_ui; base = base_ui; rp = rp_ui; cs = cs_ui; n = n_ui; }
  else { b -= nb_ui; bb = bb_iu; base = base_iu; rp = rp_iu; cs = cs_iu; n = n_iu; }
  int lo = base[b], hi = base[b + 1];
  __shared__ int h[256], sh[256], cur[256];
  int t = threadIdx.x;
  h[t] = 0;
  __syncthreads();
  for (int j = lo + t; j < hi; j += 256) atomicAdd(&h[(bb[j] >> 16) & 255], 1);
  __syncthreads();
  int v = h[t];
  sh[t] = v;
  __syncthreads();
  for (int off = 1; off < 256; off <<= 1) {
    int u = (t >= off) ? sh[t - off] : 0;
    __syncthreads();
    sh[t] += u;
    __syncthreads();
  }
  int ex = lo + sh[t] - v;
  int gd = (b << 8) + t;
  if (gd < n) rp[gd] = ex;
  cur[t] = ex;
  __syncthreads();
  for (int j = lo + t; j < hi; j += 256) {
    u32 pr = bb[j];
    int p = atomicAdd(&cur[(pr >> 16) & 255], 1);
    cs[p] = (int)(pr & 0xffffu);
  }
}

// ---------------------------------------------------------------------------
// Merged 3-way projection for BOTH node sets. blockIdx.x < gu -> users,
// else items. blockIdx.y: 0 -> q (fp8, Tqv bytes 0..127), 1 -> k (bf16 into
// Tk, PRE-SCALED by KSCALE = 1/sqrt(D)*log2(e)), 2 -> v (fp8, Tqv bytes
// 128..255). Tqv row = 256 B: [q0..q127 | v0..v127] (plain halves; with the
// 256B-aligned base each half is ONE 128B line — same fetch as interleaved).
// Epilogue: encoded outputs staged in reused wlds, then coalesced dense
// 16B stores (R8-validated: ~20us faster than strided 8B stores).
// MFMA layouts (m89/m91-verified): A[m=lane&15][k=quad*8+j];
// B[k=quad*8+j][n=lane&15]; C/D: col=lane&15, row=quad*4+reg.
// ---------------------------------------------------------------------------
__global__ __launch_bounds__(256) void gemm3(
    const u16* __restrict__ xu, const u16* __restrict__ xi,
    const u16* __restrict__ wqu, const u16* __restrict__ wku, const u16* __restrict__ wvu,
    const float* __restrict__ bqu, const float* __restrict__ bku, const float* __restrict__ bvu,
    const u16* __restrict__ wqi, const u16* __restrict__ wki, const u16* __restrict__ wvi,
    const float* __restrict__ bqi, const float* __restrict__ bki, const float* __restrict__ bvi,
    u8* __restrict__ Tqv_u, u16* __restrict__ Tk_u,
    u8* __restrict__ Tqv_i, u16* __restrict__ Tk_i,
    int gu, int nu, int ni) {
  __shared__ __align__(16) u16 wlds[128 * 136];
  int bx = blockIdx.x, y = blockIdx.y;
  bool item = bx >= gu;
  if (item) bx -= gu;
  const u16* x = item ? xi : xu;
  int nrows = item ? ni : nu;
  const u16* wt; const float* bias;
  if (y == 0)      { wt = item ? wqi : wqu; bias = item ? bqi : bqu; }
  else if (y == 1) { wt = item ? wki : wku; bias = item ? bki : bku; }
  else             { wt = item ? wvi : wvu; bias = item ? bvi : bvu; }
  u8* Tqv = item ? Tqv_i : Tqv_u;
  u16* Tk = item ? Tk_i : Tk_u;

  int t = threadIdx.x;
#pragma unroll
  for (int i = 0; i < 8; ++i) {
    int idx = t + 256 * i;
    int n = idx >> 4, kc = idx & 15;
    ((bf16x8*)wlds)[n * 17 + kc] = ((const bf16x8*)wt)[idx];
  }
  __syncthreads();
  int wave = t >> 6, lane = t & 63;
  int m = lane & 15, quad = lane >> 4;
  int row0 = bx * 64 + wave * 16;
  int arow = row0 + m;
  const bf16x8* xv = (const bf16x8*)(x + (size_t)(arow < nrows ? arow : 0) * D);
  f32x4 acc[8];
#pragma unroll
  for (int n = 0; n < 8; ++n) acc[n] = (f32x4){0.f, 0.f, 0.f, 0.f};
#pragma unroll
  for (int kk = 0; kk < 4; ++kk) {
    bf16x8 a = xv[kk * 4 + quad];
#pragma unroll
    for (int n = 0; n < 8; ++n) {
      bf16x8 b = ((const bf16x8*)wlds)[(n * 16 + m) * 17 + kk * 4 + quad];
      acc[n] = __builtin_amdgcn_mfma_f32_16x16x32_bf16(a, b, acc[n], 0, 0, 0);
    }
  }
  __syncthreads();  // all waves done reading weights; wlds is reused below
  if (y == 1) {
    u16* ob = (u16*)wlds;  // [64][136] u16 (stride 136: 16B-aligned rows)
#pragma unroll
    for (int n = 0; n < 8; ++n) {
      float bb = bias[n * 16 + m];
#pragma unroll
      for (int r = 0; r < 4; ++r) {
        int rl = wave * 16 + quad * 4 + r;
        ob[rl * 136 + n * 16 + m] = f2b((acc[n][r] + bb) * KSCALE);
      }
    }
    __syncthreads();
    int rl = t >> 2, c0 = (t & 3) * 32;
    int orow = bx * 64 + rl;
    if (orow < nrows) {
      const uint4* src = (const uint4*)(ob + rl * 136 + c0);
      uint4* dst = (uint4*)(Tk + (size_t)orow * 128 + c0);
      dst[0] = src[0]; dst[1] = src[1]; dst[2] = src[2]; dst[3] = src[3];
    }
  } else {
    int vo = (y == 0) ? 0 : 128;
    u8* ob = (u8*)wlds;  // [64][144] u8 (stride 144: 16B-aligned rows)
#pragma unroll
    for (int n = 0; n < 8; ++n) {
      float bb = bias[n * 16 + m];
#pragma unroll
      for (int r = 0; r < 4; ++r) {
        int rl = wave * 16 + quad * 4 + r;
        ob[rl * 144 + n * 16 + m] = enc_fp8(acc[n][r] + bb);
      }
    }
    __syncthreads();
    int rl = t >> 2, c0 = (t & 3) * 32;
    int orow = bx * 64 + rl;
    if (orow < nrows) {
      const uint4* src = (const uint4*)(ob + rl * 144 + c0);
      uint4* dst = (uint4*)(Tqv + (size_t)orow * 256 + vo + c0);
      dst[0] = src[0]; dst[1] = src[1];
    }
  }
}

// ---------------------------------------------------------------------------
// Per-edge-slot work: decode q|v fp8 (two uint2s from the same 256B row) to
// f32x2 pairs, packed dot + horizontal add, DPP 16-lane reduce (broadcast),
// leaky_relu + exp2 (k pre-scaled by 1/sqrt(D)*log2e), packed acc.
// ---------------------------------------------------------------------------
static __device__ __forceinline__ void do_edge(uint2 qw, uint2 vw, bool act,
                                               const f32x2* kx, f32x2* acc, float& z) {
  f32x2 qx[4], vx[4];
  dec8_fp8_v(qw.x, qw.y, qx);
  dec8_fp8_v(vw.x, vw.y, vx);
  f32x2 d2 = qx[0] * kx[0];
  d2 = VFMA(qx[1], kx[1], d2);
  d2 = VFMA(qx[2], kx[2], d2);
  d2 = VFMA(qx[3], kx[3], d2);
  float dot = d2.x + d2.y;
  dot = dpp_add_f<0xB1>(dot);   // + lane^1
  dot = dpp_add_f<0x4E>(dot);   // + lane^2  -> quad-of-4 uniform
  dot = dpp_add_f<0x128>(dot);  // + row_ror:8
  dot = dpp_add_f<0x124>(dot);  // + row_ror:4 -> full 16-lane sum, broadcast
  float sc = (dot > 0.f) ? dot : 0.01f * dot;  // leaky_relu (scale pre-folded)
  float p = act ? exp2f(sc) : 0.f;             // exp(leaky(score)) == exp2(sc)
  z += p;
  f32x2 p2 = {p, p};
  acc[0] = VFMA(p2, vx[0], acc[0]);
  acc[1] = VFMA(p2, vx[1], acc[1]);
  acc[2] = VFMA(p2, vx[2], acc[2]);
  acc[3] = VFMA(p2, vx[3], acc[3]);
}

// ---------------------------------------------------------------------------
// Merged CSR aggregation: ONE WAVE PER DST, 16 edge slots/iter, wave-uniform
// rem guards (R5/R7-validated structure). Tqv rows are [q|v] halves with
// 256B-ALIGNED base: per slot two 8B gathers from the same row touch exactly
// 2x128B lines (q-half line + v-half line) — same bytes as R7's single 16B
// gather from the interleaved layout. The R8/R9 FETCH=178MB regression was
// the workspace losing 256B alignment (rows straddling 3 lines), fixed in
// kernel_launch.
// ---------------------------------------------------------------------------
__global__ __launch_bounds__(256, 8) void agg_pass(
    const u8* __restrict__ Tqv_u, const u16* __restrict__ Tk_u,
    const u8* __restrict__ Tqv_i, const u16* __restrict__ Tk_i,
    const int* __restrict__ rp_ui, const int* __restrict__ cs_ui,
    const int* __restrict__ rp_iu, const int* __restrict__ cs_iu,
    float* __restrict__ agg_u, float* __restrict__ agg_i,
    float* __restrict__ zpart, int gai, int ni, int nu) {
  int bx = blockIdx.x;
  const u8* Pqv; const u16* Pk; const int* rp; const int* cs;
  float* agg; float* zp; int ndst;
  if (bx < gai) { Pqv = Tqv_u; Pk = Tk_i; rp = rp_ui; cs = cs_ui; agg = agg_i; zp = zpart; ndst = ni; }
  else { bx -= gai; Pqv = Tqv_i; Pk = Tk_u; rp = rp_iu; cs = cs_iu; agg = agg_u; zp = zpart + 1024; ndst = nu; }
  int wave = threadIdx.x >> 6, lane = threadIdx.x & 63;
  int d = bx * 4 + wave;
  int sub = lane & 15;
  int quad = lane >> 4;
  float z = 0.f;
  f32x2 acc[4] = {{0.f, 0.f}, {0.f, 0.f}, {0.f, 0.f}, {0.f, 0.f}};
  if (d < ndst) {
    bf16x8 kf = *(const bf16x8*)(Pk + (size_t)d * D + sub * 8);
    int beg = rp[d], end = rp[d + 1];
    f32x2 kx[4];
#pragma unroll
    for (int i = 0; i < 4; ++i)
      kx[i] = (f32x2){b2f((u16)((short*)&kf)[2 * i]), b2f((u16)((short*)&kf)[2 * i + 1])};
    const u8* Pq = Pqv + sub * 8;
    for (int j = beg; j < end; j += 16) {
      int rem = end - j;  // wave-uniform (>0)
      int e1 = end - 1;
      int i0 = j + quad, i1 = i0 + 4, i2 = i0 + 8, i3 = i0 + 12;
      int s0 = cs[i0 < end ? i0 : e1];
      int s1 = cs[i1 < end ? i1 : e1];
      int s2 = cs[i2 < end ? i2 : e1];
      int s3 = cs[i3 < end ? i3 : e1];
      // eight independent 8B gathers in flight before first use
      const u8* b0 = Pq + (size_t)s0 * 256;
      const u8* b1 = Pq + (size_t)s1 * 256;
      const u8* b2 = Pq + (size_t)s2 * 256;
      const u8* b3 = Pq + (size_t)s3 * 256;
      uint2 q0 = *(const uint2*)b0;
      uint2 q1 = *(const uint2*)b1;
      uint2 q2 = *(const uint2*)b2;
      uint2 q3 = *(const uint2*)b3;
      uint2 v0 = *(const uint2*)(b0 + 128);
      uint2 v1 = *(const uint2*)(b1 + 128);
      uint2 v2 = *(const uint2*)(b2 + 128);
      uint2 v3 = *(const uint2*)(b3 + 128);
      do_edge(q0, v0, i0 < end, kx, acc, z);
      if (rem > 4)  do_edge(q1, v1, i1 < end, kx, acc, z);
      if (rem > 8)  do_edge(q2, v2, i2 < end, kx, acc, z);
      if (rem > 12) do_edge(q3, v3, i3 < end, kx, acc, z);
    }
    float* af = (float*)acc;
#pragma unroll
    for (int i = 0; i < 8; ++i) {
      af[i] += __shfl_xor(af[i], 16, 64);
      af[i] += __shfl_xor(af[i], 32, 64);
    }
    if (quad == 0) {
      float* ap = agg + (size_t)d * D + sub * 8;
      __builtin_nontemporal_store((f32x4){af[0], af[1], af[2], af[3]}, (f32x4*)ap);
      __builtin_nontemporal_store((f32x4){af[4], af[5], af[6], af[7]}, (f32x4*)ap + 1);
    }
    z += __shfl_xor(z, 16, 64);
    z += __shfl_xor(z, 32, 64);
  }
  __shared__ float ps[4];
  if (lane == 0) ps[wave] = z;
  __syncthreads();
  if (threadIdx.x == 0)
    unsafeAtomicAdd(&zp[blockIdx.x & 1023], ps[0] + ps[1] + ps[2] + ps[3]);
}

// float4-vectorized, with the z reduction folded in (validated R8): each
// block redundantly reduces zpart[0..2047] (8KB, L2-resident) — removes the
// zreduce launch + serialization hop.
__global__ void update_x(const float* __restrict__ xu, const float* __restrict__ xi,
                         const float* __restrict__ aggu, const float* __restrict__ aggi,
                         const float* __restrict__ zpart,
                         float* __restrict__ ou, float* __restrict__ oi,
                         u16* __restrict__ bu, u16* __restrict__ bi,
                         int nu4, int ni4, int wb) {
  __shared__ float red0[256], red1[256];
  int t = threadIdx.x;
  float s0 = zpart[t] + zpart[t + 256] + zpart[t + 512] + zpart[t + 768];
  float s1 = zpart[1024 + t] + zpart[1280 + t] + zpart[1536 + t] + zpart[1792 + t];
  red0[t] = s0;
  red1[t] = s1;
  __syncthreads();
  for (int k = 128; k > 0; k >>= 1) {
    if (t < k) { red0[t] += red0[t + k]; red1[t] += red1[t + k]; }
    __syncthreads();
  }
  float zi = 1.0f / red0[0];  // ui edges -> item aggregation normalizer
  float zu = 1.0f / red1[0];  // iu edges -> user aggregation normalizer
  int i = blockIdx.x * 256 + t;
  const float4* xs; const float4* as; float4* os; u16* bs; float zz; int jj;
  if (i < nu4) {
    xs = (const float4*)xu; as = (const float4*)aggu; os = (float4*)ou; bs = bu;
    zz = zu; jj = i;
  } else if (i < nu4 + ni4) {
    jj = i - nu4;
    xs = (const float4*)xi; as = (const float4*)aggi; os = (float4*)oi; bs = bi;
    zz = zi;
  } else {
    return;
  }
  float4 xv = xs[jj];
  float4 av = as[jj];
  float4 v;
  v.x = xv.x + av.x * zz;
  v.y = xv.y + av.y * zz;
  v.z = xv.z + av.z * zz;
  v.w = xv.w + av.w * zz;
  os[jj] = v;
  if (wb) {
    ushort4 b;
    b.x = f2b(v.x); b.y = f2b(v.y); b.z = f2b(v.z); b.w = f2b(v.w);
    ((ushort4*)bs)[jj] = b;
  }
}

extern "C" void kernel_launch(void* const* d_in, const int* in_sizes, int n_in,
                              void* d_out, int out_size, void* d_ws, size_t ws_size,
                              hipStream_t stream) {
  const float* xu_in = (const float*)d_in[0];
  const float* xi_in = (const float*)d_in[1];
  const int* ei_ui = (const int*)d_in[2];
  const int* ei_iu = (const int*)d_in[3];
  const float* qwu = (const float*)d_in[4];
  const float* qbu = (const float*)d_in[5];
  const float* kwu = (const float*)d_in[6];
  const float* kbu = (const float*)d_in[7];
  const float* vwu = (const float*)d_in[8];
  const float* vbu = (const float*)d_in[9];
  const float* qwi = (const float*)d_in[10];
  const float* qbi = (const float*)d_in[11];
  const float* kwi = (const float*)d_in[12];
  const float* kbi = (const float*)d_in[13];
  const float* vwi = (const float*)d_in[14];
  const float* vbi = (const float*)d_in[15];
  const float* Wui = (const float*)d_in[16];
  const float* Wiu = (const float*)d_in[17];

  int NU = in_sizes[0] / D;
  int NI = in_sizes[1] / D;
  int E  = in_sizes[2] / 2;

  // workspace layout (16B-aligned chunks)
  char* w = (char*)d_ws;
  float* agg_u = (float*)w;  w += (size_t)NU * D * 4;
  float* agg_i = (float*)w;  w += (size_t)NI * D * 4;
  // zero region: bcnt_ui[256], bcnt_iu[256], zpart[4096] contiguous
  int* bcnt_ui = (int*)w;    w += 256 * 4;
  int* bcnt_iu = (int*)w;    w += 256 * 4;
  float* zpart = (float*)w;  w += 4096 * 4;
  float* bq    = (float*)w;  w += 4 * D * 4;
  int* base_ui = (int*)w;    w += 260 * 4;
  int* base_iu = (int*)w;    w += 260 * 4;
  int* cur_ui  = (int*)w;    w += 256 * 4;
  int* cur_iu  = (int*)w;    w += 256 * 4;
  int* rp_ui = (int*)w;      w += (size_t)(NI + 4) * 4;
  int* rp_iu = (int*)w;      w += (size_t)(NU + 4) * 4;
  int* cs_ui = (int*)w;      w += (size_t)E * 4;
  int* cs_iu = (int*)w;      w += (size_t)E * 4;
  u32* bb_ui = (u32*)w;      w += (size_t)E * 4;
  u32* bb_iu = (u32*)w;      w += (size_t)E * 4;
  u16* Mt  = (u16*)w;        w += (size_t)4 * D * D * 2;
  u16* Wb  = (u16*)w;        w += (size_t)8 * D * D * 2;
  u16* xub = (u16*)w;        w += (size_t)NU * D * 2;
  u16* xib = (u16*)w;        w += (size_t)NI * D * 2;
  // CRITICAL: 256B-align the T-buffers. R8/R9 lost this (removing zinv's
  // 64B shifted Tqv to base%256==192), making every random 256B-row gather
  // straddle 3x128B lines instead of 2 -> FETCH 130->178MB (+37%). All four
  // T-buffer sizes are multiples of 256, so one align fixes them all.
  w = (char*)(((uintptr_t)w + 255) & ~(uintptr_t)255);
  u16* Tk_u = (u16*)w;       w += (size_t)NU * D * 2;
  u16* Tk_i = (u16*)w;       w += (size_t)NI * D * 2;
  u8* Tqv_u = (u8*)w;        w += (size_t)NU * 256;
  u8* Tqv_i = (u8*)w;

  float* out_u = (float*)d_out;
  float* out_i = out_u + (size_t)NU * D;

  prep_fused<<<dim3(128, 4), 128, 0, stream>>>(qwu, qbu, qwi, qbi, Wui, Wiu, Mt, bq);
  cast_w<<<dim3(128, 4), 256, 0, stream>>>(kwu, kwi, vwu, vwi, Wb);
  cast_x<<<(NU * D / 2 + 255) / 256, 256, 0, stream>>>(xu_in, xub, NU * D / 2);
  cast_x<<<(NI * D / 2 + 255) / 256, 256, 0, stream>>>(xi_in, xib, NI * D / 2);

  // ---- CSR build via 2-level bucket sort (edges constant across layers) ----
  int nb_ui = (NI + 255) >> 8;
  int nb_iu = (NU + 255) >> 8;
  zero_i<<<18, 256, 0, stream>>>(bcnt_ui, 512 + 4096);
  int geb = (E + 1023) / 1024;
  bhist<<<dim3(geb, 2), 256, 0, stream>>>(ei_ui + E, ei_iu + E, bcnt_ui, bcnt_iu, E);
  bscan<<<1, 256, 0, stream>>>(bcnt_ui, bcnt_iu, base_ui, base_iu, cur_ui, cur_iu,
                               rp_ui, rp_iu, nb_ui, nb_iu, NI, NU, E);
  bscatter<<<dim3(geb, 2), 256, 0, stream>>>(ei_ui, ei_ui + E, ei_iu, ei_iu + E,
                                             cur_ui, cur_iu, bb_ui, bb_iu, E);
  bsort<<<nb_ui + nb_iu, 256, 0, stream>>>(bb_ui, bb_iu, base_ui, base_iu,
                                           rp_ui, rp_iu, cs_ui, cs_iu, nb_ui, NI, NU);

  int gu = (NU + 63) / 64, gi = (NI + 63) / 64;
  int gau = (NU + 3) / 4, gai = (NI + 3) / 4;
  int nu4 = NU * D / 4, ni4 = NI * D / 4;
  int gup = (nu4 + ni4 + 255) / 256;

  for (int l = 0; l < 2; ++l) {
    gemm3<<<dim3(gu + gi, 3), 256, 0, stream>>>(
        xub, xib,
        Mt + (size_t)l * D * D, Wb + (size_t)(0 + l) * D * D, Wb + (size_t)(4 + l) * D * D,
        bq + l * D, kbu + l * D, vbu + l * D,
        Mt + (size_t)(2 + l) * D * D, Wb + (size_t)(2 + l) * D * D, Wb + (size_t)(6 + l) * D * D,
        bq + (2 + l) * D, kbi + l * D, vbi + l * D,
        Tqv_u, Tk_u, Tqv_i, Tk_i, gu, NU, NI);
    agg_pass<<<gai + gau, 256, 0, stream>>>(
        Tqv_u, Tk_u, Tqv_i, Tk_i, rp_ui, cs_ui, rp_iu, cs_iu,
        agg_u, agg_i, zpart + (size_t)l * 2 * 1024, gai, NI, NU);
    if (l == 0)
      update_x<<<gup, 256, 0, stream>>>(xu_in, xi_in, agg_u, agg_i,
                                        zpart + (size_t)l * 2 * 1024,
                                        out_u, out_i, xub, xib, nu4, ni4, 1);
    else
      update_x<<<gup, 256, 0, stream>>>(out_u, out_i, agg_u, agg_i,
                                        zpart + (size_t)l * 2 * 1024,
                                        out_u, out_i, nullptr, nullptr, nu4, ni4, 0);
  }
}